// Round 2
// baseline (169.747 us; speedup 1.0000x reference)
//
#include <hip/hip_runtime.h>
#include <math.h>

// Keep mul/add rounding deterministic in the discrete-sensitive chains
// (radius -> quantile -> grid). Score math uses explicit fmaf.
#pragma clang fp contract(off)

#define G_N 2048
#define P_N 16384
#define K_TOP 8
#define NCHUNK 8
#define CHUNK 256            // gaussians per chunk (G_N / NCHUNK)
#define GS 20                // floats per gaussian struct (5 x float4)
#define GSOFF 16             // header: [0..6] stats, [8..10] gmin, [11] voxel
#define CANDOFF (GSOFF + G_N * GS)   // float index; float2 records follow

__device__ __forceinline__ void quat_R(const float* quat, int g, float R[3][3]) {
    float q0 = quat[g * 4 + 0], q1 = quat[g * 4 + 1], q2 = quat[g * 4 + 2], q3 = quat[g * 4 + 3];
    float nrm = sqrtf(q0 * q0 + q1 * q1 + q2 * q2 + q3 * q3);
    float w = q0 / nrm, x = q1 / nrm, y = q2 / nrm, z = q3 / nrm;
    R[0][0] = 1.0f - 2.0f * (y * y + z * z);
    R[0][1] = 2.0f * (x * y - w * z);
    R[0][2] = 2.0f * (x * z + w * y);
    R[1][0] = 2.0f * (x * y + w * z);
    R[1][1] = 1.0f - 2.0f * (x * x + z * z);
    R[1][2] = 2.0f * (y * z - w * x);
    R[2][0] = 2.0f * (x * z - w * y);
    R[2][1] = 2.0f * (y * z + w * x);
    R[2][2] = 1.0f - 2.0f * (x * x + y * y);
}

// radius along axis a — shared by k_stats and k_prep, identical rounding.
__device__ __forceinline__ float radius_axis(const float R[3][3], float s2x, float s2y, float s2z, int a) {
    float dc = (R[a][0] * R[a][0]) * s2x + (R[a][1] * R[a][1]) * s2y + (R[a][2] * R[a][2]) * s2z;
    return sqrtf(7.8147279f) * sqrtf(dc);
}

// Stats: 7 blocks. Block computes its stat array inline, bitonic-sorts in LDS,
// emits the interpolated order statistic to ws[which].
// 0-2: quantile(min_c[:,a],0.01); 3-5: quantile(max_c[:,a],0.99); 6: median(radius_x)
__global__ __launch_bounds__(1024) void k_stats(const float* __restrict__ pos,
                                                const float* __restrict__ scl,
                                                const float* __restrict__ quat,
                                                float* __restrict__ ws) {
    __shared__ float buf[G_N];
    int which = blockIdx.x;
    int tid = threadIdx.x;
    int a = (which < 3) ? which : (which < 6 ? which - 3 : 0);
    for (int g = tid; g < G_N; g += 1024) {
        float R[3][3];
        quat_R(quat, g, R);
        float sx = scl[g * 3 + 0], sy = scl[g * 3 + 1], sz = scl[g * 3 + 2];
        float rad = radius_axis(R, sx * sx, sy * sy, sz * sz, a);
        float v;
        if (which < 3)      v = pos[g * 3 + a] - rad;
        else if (which < 6) v = pos[g * 3 + a] + rad;
        else                v = rad;
        buf[g] = v;
    }
    __syncthreads();
    for (int k = 2; k <= G_N; k <<= 1) {
        for (int j = k >> 1; j > 0; j >>= 1) {
            for (int i = tid; i < G_N; i += 1024) {
                int partner = i ^ j;
                if (partner > i) {
                    bool up = ((i & k) == 0);
                    float va = buf[i], vb = buf[partner];
                    if ((va > vb) == up) { buf[i] = vb; buf[partner] = va; }
                }
            }
            __syncthreads();
        }
    }
    if (tid == 0) {
        float qq;
        if (which < 3) qq = 0.01f * 2047.0f;
        else if (which < 6) qq = 0.99f * 2047.0f;
        else qq = 0.5f * 2047.0f;
        int lo = (int)floorf(qq);
        float fr = qq - (float)lo;
        ws[which] = buf[lo] * (1.0f - fr) + buf[lo + 1] * fr;
    }
}

// Prep: per-gaussian struct. Grid params recomputed per-thread from ws[0..6]
// (same f32 expressions as before => same bits). Thread 0 publishes gmin/vox.
// Struct (20 floats): C[9], b[3], c0, log_norm, gmin[3] (int bits, oversized-
// folded to INT_MIN), gmax[3] (int bits, folded to INT_MAX).
__global__ void k_prep(const float* __restrict__ pos, const float* __restrict__ scl,
                       const float* __restrict__ quat, float* __restrict__ ws) {
    int g = blockIdx.x * blockDim.x + threadIdx.x;
    if (g >= G_N) return;
    float gmn[3], vox;
#pragma unroll
    for (int t = 0; t < 3; ++t) {
        float lo = ws[t], hi = ws[3 + t];
        float size = hi - lo;
        gmn[t] = lo - 0.1f * size;
    }
    vox = ws[6] * 3.0f;
    if (g == 0) { ws[8] = gmn[0]; ws[9] = gmn[1]; ws[10] = gmn[2]; ws[11] = vox; }

    float R[3][3];
    quat_R(quat, g, R);
    float sx = scl[g * 3 + 0], sy = scl[g * 3 + 1], sz = scl[g * 3 + 2];
    float s2x = sx * sx, s2y = sy * sy, s2z = sz * sz;

    int gmini[3], gmaxi[3];
    long long nv = 1;
#pragma unroll
    for (int t = 0; t < 3; ++t) {
        float rad = radius_axis(R, s2x, s2y, s2z, t);
        float p = pos[g * 3 + t];
        float mn = p - rad, mx = p + rad;
        int lo = (int)floorf((mn - gmn[t]) / vox);
        int hi = (int)floorf((mx - gmn[t]) / vox);
        lo = lo < 0 ? 0 : (lo > 1023 ? 1023 : lo);
        hi = hi < 0 ? 0 : (hi > 1023 ? 1023 : hi);
        gmini[t] = lo; gmaxi[t] = hi;
        nv *= (long long)(hi - lo + 1);
    }
    bool oversized = nv > 64;
#pragma unroll
    for (int t = 0; t < 3; ++t) {
        if (oversized) { gmini[t] = INT_MIN; gmaxi[t] = INT_MAX; }
    }

    float inv2x = 1.0f / s2x, inv2y = 1.0f / s2y, inv2z = 1.0f / s2z;
    float C[3][3];
#pragma unroll
    for (int i = 0; i < 3; ++i) {
        float t0 = R[i][0] * inv2x, t1 = R[i][1] * inv2y, t2 = R[i][2] * inv2z;
#pragma unroll
        for (int k = 0; k < 3; ++k)
            C[i][k] = t0 * R[k][0] + t1 * R[k][1] + t2 * R[k][2];
    }
    float px = pos[g * 3 + 0], py = pos[g * 3 + 1], pz = pos[g * 3 + 2];
    float b0 = C[0][0] * px + C[0][1] * py + C[0][2] * pz;
    float b1 = C[1][0] * px + C[1][1] * py + C[1][2] * pz;
    float b2 = C[2][0] * px + C[2][1] * py + C[2][2] * pz;
    float c0 = b0 * px + b1 * py + b2 * pz;
    float log_norm = -2.7568155996140179f - (logf(sx) + logf(sy) + logf(sz));

    float4* o = (float4*)(ws + GSOFF + g * GS);
    o[0] = make_float4(C[0][0], C[0][1], C[0][2], C[1][0]);
    o[1] = make_float4(C[1][1], C[1][2], C[2][0], C[2][1]);
    o[2] = make_float4(C[2][2], b0, b1, b2);
    o[3] = make_float4(c0, log_norm, __int_as_float(gmini[0]), __int_as_float(gmini[1]));
    o[4] = make_float4(__int_as_float(gmini[2]), __int_as_float(gmaxi[0]),
                       __int_as_float(gmaxi[1]), __int_as_float(gmaxi[2]));
}

// Score: grid (P/128, NCHUNK), 256 threads = 128 points x 2 lanes.
// Lane pair splits the 256-gaussian chunk; pair-merge via shfl_xor; even lane
// writes top-8 to cand[(c*8+slot)*P + p] (float2 planes, coalesced).
__global__ __launch_bounds__(256) void k_score(const float* __restrict__ pts, float* ws) {
    __shared__ float4 lg[CHUNK * 5];
    int c = blockIdx.y;
    const float4* gsrc = (const float4*)(ws + GSOFF + c * CHUNK * GS);
    for (int i = threadIdx.x; i < CHUNK * 5; i += 256) lg[i] = gsrc[i];
    __syncthreads();

    int half = threadIdx.x & 1;
    int p = blockIdx.x * 128 + (threadIdx.x >> 1);
    float px = pts[p * 3 + 0], py = pts[p * 3 + 1], pz = pts[p * 3 + 2];
    float gm0 = ws[8], gm1 = ws[9], gm2 = ws[10], vox = ws[11];
    int pvx = (int)floorf((px - gm0) / vox);
    int pvy = (int)floorf((py - gm1) / vox);
    int pvz = (int)floorf((pz - gm2) / vox);
    float pp0 = px * px, pp1 = px * py, pp2 = px * pz;
    float pp4 = py * py, pp5 = py * pz, pp8 = pz * pz;

    float tv[K_TOP];
    int ti[K_TOP];
#pragma unroll
    for (int j = 0; j < K_TOP; ++j) { tv[j] = -INFINITY; ti[j] = 0x7fffffff; }

    int kbeg = half * (CHUNK / 2), kend = kbeg + (CHUNK / 2);
#pragma unroll 2
    for (int k = kbeg; k < kend; ++k) {
        float4 a0 = lg[k * 5 + 0];
        float4 a1 = lg[k * 5 + 1];
        float4 a2 = lg[k * 5 + 2];
        float4 a3 = lg[k * 5 + 3];
        float4 a4 = lg[k * 5 + 4];
        float t = pp0 * a0.x;
        t = fmaf(pp1, a0.y, t);
        t = fmaf(pp2, a0.z, t);
        t = fmaf(pp1, a0.w, t);
        t = fmaf(pp4, a1.x, t);
        t = fmaf(pp5, a1.y, t);
        t = fmaf(pp2, a1.z, t);
        t = fmaf(pp5, a1.w, t);
        t = fmaf(pp8, a2.x, t);
        float d = px * a2.y;
        d = fmaf(py, a2.z, d);
        d = fmaf(pz, a2.w, d);
        float quad = fmaf(-2.0f, d, t) + a3.x;
        float sc = fmaf(-0.5f, quad, a3.y);
        int g0 = __float_as_int(a3.z), g1 = __float_as_int(a3.w), g2 = __float_as_int(a4.x);
        int h0 = __float_as_int(a4.y), h1 = __float_as_int(a4.z), h2 = __float_as_int(a4.w);
        bool inb = (pvx >= g0) & (pvx <= h0) & (pvy >= g1) & (pvy <= h1) & (pvz >= g2) & (pvz <= h2);
        sc = inb ? sc : -INFINITY;
        if (sc > tv[K_TOP - 1]) {
            tv[K_TOP - 1] = sc;
            ti[K_TOP - 1] = c * CHUNK + k;
#pragma unroll
            for (int j = K_TOP - 1; j > 0; --j) {
                if (tv[j] > tv[j - 1]) {
                    float fv = tv[j]; tv[j] = tv[j - 1]; tv[j - 1] = fv;
                    int iv = ti[j]; ti[j] = ti[j - 1]; ti[j - 1] = iv;
                }
            }
        }
    }

    // exchange partner's sorted list
    float ov[K_TOP];
    int oi[K_TOP];
#pragma unroll
    for (int j = 0; j < K_TOP; ++j) {
        ov[j] = __shfl_xor(tv[j], 1);
        oi[j] = __shfl_xor(ti[j], 1);
    }
    // merge two sorted-desc lists -> top-8 (ties: lower idx first)
    float mv[K_TOP];
    int mi[K_TOP];
    int ia = 0, ib = 0;
#pragma unroll
    for (int j = 0; j < K_TOP; ++j) {
        bool ta = (tv[ia] > ov[ib]) || (tv[ia] == ov[ib] && ti[ia] < oi[ib]);
        if (ta) { mv[j] = tv[ia]; mi[j] = ti[ia]; ++ia; }
        else    { mv[j] = ov[ib]; mi[j] = oi[ib]; ++ib; }
    }
    if (half == 0) {
        float2* cand = (float2*)(ws + CANDOFF);
#pragma unroll
        for (int j = 0; j < K_TOP; ++j)
            cand[(size_t)(c * K_TOP + j) * P_N + p] = make_float2(mv[j], __int_as_float(mi[j]));
    }
}

// Merge: 256 blocks x 64 threads; fold NCHUNK sorted lists per point.
__global__ __launch_bounds__(64) void k_merge(const float* __restrict__ ws, float* __restrict__ out) {
    int p = blockIdx.x * 64 + threadIdx.x;
    const float2* cand = (const float2*)(ws + CANDOFF);
    float tv[K_TOP];
    int ti[K_TOP];
#pragma unroll
    for (int j = 0; j < K_TOP; ++j) { tv[j] = -INFINITY; ti[j] = 0x7fffffff; }
    for (int c = 0; c < NCHUNK; ++c) {
#pragma unroll
        for (int j = 0; j < K_TOP; ++j) {
            float2 r = cand[(size_t)(c * K_TOP + j) * P_N + p];
            float v = r.x;
            int idx = __float_as_int(r.y);
            bool better = (v > tv[K_TOP - 1]) || (v == tv[K_TOP - 1] && idx < ti[K_TOP - 1]);
            if (better) {
                tv[K_TOP - 1] = v;
                ti[K_TOP - 1] = idx;
#pragma unroll
                for (int t = K_TOP - 1; t > 0; --t) {
                    bool sw = (tv[t] > tv[t - 1]) || (tv[t] == tv[t - 1] && ti[t] < ti[t - 1]);
                    if (sw) {
                        float fv = tv[t]; tv[t] = tv[t - 1]; tv[t - 1] = fv;
                        int iv = ti[t]; ti[t] = ti[t - 1]; ti[t - 1] = iv;
                    }
                }
            }
        }
    }
#pragma unroll
    for (int j = 0; j < K_TOP; ++j) {
        bool fin = tv[j] > -INFINITY;
        out[p * K_TOP + j] = fin ? (float)ti[j] : -1.0f;
        out[P_N * K_TOP + p * K_TOP + j] = fin ? expf(tv[j]) : 0.0f;
    }
}

extern "C" void kernel_launch(void* const* d_in, const int* in_sizes, int n_in,
                              void* d_out, int out_size, void* d_ws, size_t ws_size,
                              hipStream_t stream) {
    const float* pos = (const float*)d_in[0];
    const float* scl = (const float*)d_in[1];
    const float* quat = (const float*)d_in[2];
    const float* pts = (const float*)d_in[3];
    float* ws = (float*)d_ws;
    float* out = (float*)d_out;

    k_stats<<<dim3(7), dim3(1024), 0, stream>>>(pos, scl, quat, ws);
    k_prep<<<dim3(G_N / 256), dim3(256), 0, stream>>>(pos, scl, quat, ws);
    k_score<<<dim3(P_N / 128, NCHUNK), dim3(256), 0, stream>>>(pts, ws);
    k_merge<<<dim3(P_N / 64), dim3(64), 0, stream>>>(ws, out);
}

// Round 3
// 139.339 us; speedup vs baseline: 1.2182x; 1.2182x over previous
//
#include <hip/hip_runtime.h>
#include <math.h>

// Keep mul/add rounding deterministic in the discrete-sensitive chains
// (radius -> quantile -> grid). Score math uses explicit fmaf.
#pragma clang fp contract(off)

#define G_N 2048
#define P_N 16384
#define K_TOP 8
#define NCHUNK 8
#define CHUNK 256            // gaussians per chunk (G_N / NCHUNK)
#define BOXOFF 16            // u32 x4 per gaussian: {A_lo, A_hi, B_lo, B_hi}
#define GDOFF (BOXOFF + G_N * 4)        // 16 floats per gaussian (4 x float4)
#define CANDOFF (GDOFF + G_N * 16)      // float2 planes [(c*8+j)*P + p]

// SWAR guard bits: fields at bits 0/21/42, guard = bit 20 of each field.
#define GUARD64 ((1ull << 20) | (1ull << 41) | (1ull << 62))

__device__ __forceinline__ void quat_R(const float* quat, int g, float R[3][3]) {
    float q0 = quat[g * 4 + 0], q1 = quat[g * 4 + 1], q2 = quat[g * 4 + 2], q3 = quat[g * 4 + 3];
    float nrm = sqrtf(q0 * q0 + q1 * q1 + q2 * q2 + q3 * q3);
    float w = q0 / nrm, x = q1 / nrm, y = q2 / nrm, z = q3 / nrm;
    R[0][0] = 1.0f - 2.0f * (y * y + z * z);
    R[0][1] = 2.0f * (x * y - w * z);
    R[0][2] = 2.0f * (x * z + w * y);
    R[1][0] = 2.0f * (x * y + w * z);
    R[1][1] = 1.0f - 2.0f * (x * x + z * z);
    R[1][2] = 2.0f * (y * z - w * x);
    R[2][0] = 2.0f * (x * z - w * y);
    R[2][1] = 2.0f * (y * z + w * x);
    R[2][2] = 1.0f - 2.0f * (x * x + y * y);
}

__device__ __forceinline__ float radius_axis(const float R[3][3], float s2x, float s2y, float s2z, int a) {
    float dc = (R[a][0] * R[a][0]) * s2x + (R[a][1] * R[a][1]) * s2y + (R[a][2] * R[a][2]) * s2z;
    return sqrtf(7.8147279f) * sqrtf(dc);
}

// Stats: 7 blocks; recompute stat array inline, bitonic sort in LDS, emit quantile.
__global__ __launch_bounds__(1024) void k_stats(const float* __restrict__ pos,
                                                const float* __restrict__ scl,
                                                const float* __restrict__ quat,
                                                float* __restrict__ ws) {
    __shared__ float buf[G_N];
    int which = blockIdx.x;
    int tid = threadIdx.x;
    int a = (which < 3) ? which : (which < 6 ? which - 3 : 0);
    for (int g = tid; g < G_N; g += 1024) {
        float R[3][3];
        quat_R(quat, g, R);
        float sx = scl[g * 3 + 0], sy = scl[g * 3 + 1], sz = scl[g * 3 + 2];
        float rad = radius_axis(R, sx * sx, sy * sy, sz * sz, a);
        float v;
        if (which < 3)      v = pos[g * 3 + a] - rad;
        else if (which < 6) v = pos[g * 3 + a] + rad;
        else                v = rad;
        buf[g] = v;
    }
    __syncthreads();
    for (int k = 2; k <= G_N; k <<= 1) {
        for (int j = k >> 1; j > 0; j >>= 1) {
            for (int i = tid; i < G_N; i += 1024) {
                int partner = i ^ j;
                if (partner > i) {
                    bool up = ((i & k) == 0);
                    float va = buf[i], vb = buf[partner];
                    if ((va > vb) == up) { buf[i] = vb; buf[partner] = va; }
                }
            }
            __syncthreads();
        }
    }
    if (tid == 0) {
        float qq;
        if (which < 3) qq = 0.01f * 2047.0f;
        else if (which < 6) qq = 0.99f * 2047.0f;
        else qq = 0.5f * 2047.0f;
        int lo = (int)floorf(qq);
        float fr = qq - (float)lo;
        ws[which] = buf[lo] * (1.0f - fr) + buf[lo + 1] * fr;
    }
}

// Prep: packed SWAR boxes + score structs. Grid params recomputed per-thread
// (same f32 chain as k_stats consumers => identical bits); g==0 publishes them.
__global__ void k_prep(const float* __restrict__ pos, const float* __restrict__ scl,
                       const float* __restrict__ quat, float* __restrict__ ws) {
    int g = blockIdx.x * blockDim.x + threadIdx.x;
    if (g >= G_N) return;
    float gmn[3], vox;
#pragma unroll
    for (int t = 0; t < 3; ++t) {
        float lo = ws[t], hi = ws[3 + t];
        float size = hi - lo;
        gmn[t] = lo - 0.1f * size;
    }
    vox = ws[6] * 3.0f;
    if (g == 0) { ws[8] = gmn[0]; ws[9] = gmn[1]; ws[10] = gmn[2]; ws[11] = vox; }

    float R[3][3];
    quat_R(quat, g, R);
    float sx = scl[g * 3 + 0], sy = scl[g * 3 + 1], sz = scl[g * 3 + 2];
    float s2x = sx * sx, s2y = sy * sy, s2z = sz * sz;

    int gmini[3], gmaxi[3];
    long long nv = 1;
#pragma unroll
    for (int t = 0; t < 3; ++t) {
        float rad = radius_axis(R, s2x, s2y, s2z, t);
        float p = pos[g * 3 + t];
        int lo = (int)floorf(((p - rad) - gmn[t]) / vox);
        int hi = (int)floorf(((p + rad) - gmn[t]) / vox);
        lo = lo < 0 ? 0 : (lo > 1023 ? 1023 : lo);
        hi = hi < 0 ? 0 : (hi > 1023 ? 1023 : hi);
        gmini[t] = lo; gmaxi[t] = hi;
        nv *= (long long)(hi - lo + 1);
    }
    bool oversized = nv > 64;
    if (oversized) {
        gmini[0] = gmini[1] = gmini[2] = 0;
        gmaxi[0] = gmaxi[1] = gmaxi[2] = 2047;   // passes the 1024 out-of-range sentinel too
    }
    unsigned long long A = (unsigned long long)gmini[0]
                         | ((unsigned long long)gmini[1] << 21)
                         | ((unsigned long long)gmini[2] << 42);
    unsigned long long B = ((unsigned long long)gmaxi[0]
                         | ((unsigned long long)gmaxi[1] << 21)
                         | ((unsigned long long)gmaxi[2] << 42)) | GUARD64;
    uint4* bx = (uint4*)((unsigned int*)ws + BOXOFF);
    bx[g] = make_uint4((unsigned)(A & 0xffffffffu), (unsigned)(A >> 32),
                       (unsigned)(B & 0xffffffffu), (unsigned)(B >> 32));

    float inv2x = 1.0f / s2x, inv2y = 1.0f / s2y, inv2z = 1.0f / s2z;
    float C[3][3];
#pragma unroll
    for (int i = 0; i < 3; ++i) {
        float t0 = R[i][0] * inv2x, t1 = R[i][1] * inv2y, t2 = R[i][2] * inv2z;
#pragma unroll
        for (int k = 0; k < 3; ++k)
            C[i][k] = t0 * R[k][0] + t1 * R[k][1] + t2 * R[k][2];
    }
    float px = pos[g * 3 + 0], py = pos[g * 3 + 1], pz = pos[g * 3 + 2];
    float b0 = C[0][0] * px + C[0][1] * py + C[0][2] * pz;
    float b1 = C[1][0] * px + C[1][1] * py + C[1][2] * pz;
    float b2 = C[2][0] * px + C[2][1] * py + C[2][2] * pz;
    float c0 = b0 * px + b1 * py + b2 * pz;
    float log_norm = -2.7568155996140179f - (logf(sx) + logf(sy) + logf(sz));

    float4* o = (float4*)(ws + GDOFF + g * 16);
    o[0] = make_float4(C[0][0], C[0][1], C[0][2], C[1][0]);
    o[1] = make_float4(C[1][1], C[1][2], C[2][0], C[2][1]);
    o[2] = make_float4(C[2][2], b0, b1, b2);
    o[3] = make_float4(c0, log_norm, 0.0f, 0.0f);
}

// merge two sorted-desc (val, idx-asc-tie) top-8 lists in registers
__device__ __forceinline__ void merge8(float tv[K_TOP], int ti[K_TOP],
                                       const float ov[K_TOP], const int oi[K_TOP]) {
    float mv[K_TOP];
    int mi[K_TOP];
    int ia = 0, ib = 0;
#pragma unroll
    for (int j = 0; j < K_TOP; ++j) {
        bool ta = (tv[ia] > ov[ib]) || (tv[ia] == ov[ib] && ti[ia] < oi[ib]);
        if (ta) { mv[j] = tv[ia]; mi[j] = ti[ia]; ++ia; }
        else    { mv[j] = ov[ib]; mi[j] = oi[ib]; ++ib; }
    }
#pragma unroll
    for (int j = 0; j < K_TOP; ++j) { tv[j] = mv[j]; ti[j] = mi[j]; }
}

// Score: grid (P/64, NCHUNK), 256 threads = 64 points x 4 sub-lanes (interleaved k).
// LDS: 256 packed boxes (4 KB). Score data fetched from global only on mask hit.
__global__ __launch_bounds__(256) void k_score(const float* __restrict__ pts, float* ws) {
    __shared__ uint4 boxes_s[CHUNK];
    int c = blockIdx.y;
    const uint4* bsrc = (const uint4*)((unsigned int*)ws + BOXOFF) + c * CHUNK;
    boxes_s[threadIdx.x] = bsrc[threadIdx.x];
    __syncthreads();

    int sub = threadIdx.x & 3;
    int p = blockIdx.x * 64 + (threadIdx.x >> 2);
    float px = pts[p * 3 + 0], py = pts[p * 3 + 1], pz = pts[p * 3 + 2];
    float gm0 = ws[8], gm1 = ws[9], gm2 = ws[10], vox = ws[11];
    int pvx = (int)floorf((px - gm0) / vox);
    int pvy = (int)floorf((py - gm1) / vox);
    int pvz = (int)floorf((pz - gm2) / vox);
    // out-of-range sentinel 1024: fails every real box (h<=1023), passes oversized (h=2047)
    unsigned fx = (pvx < 0 || pvx > 1023) ? 1024u : (unsigned)pvx;
    unsigned fy = (pvy < 0 || pvy > 1023) ? 1024u : (unsigned)pvy;
    unsigned fz = (pvz < 0 || pvz > 1023) ? 1024u : (unsigned)pvz;
    unsigned long long PV = (unsigned long long)fx
                          | ((unsigned long long)fy << 21)
                          | ((unsigned long long)fz << 42);
    unsigned long long PVG = PV | GUARD64;

    float pp0 = px * px, pp1 = px * py, pp2 = px * pz;
    float pp4 = py * py, pp5 = py * pz, pp8 = pz * pz;

    float tv[K_TOP];
    int ti[K_TOP];
#pragma unroll
    for (int j = 0; j < K_TOP; ++j) { tv[j] = -INFINITY; ti[j] = 0x7fffffff; }

    const float4* gd = (const float4*)(ws + GDOFF);
#pragma unroll 8
    for (int t = 0; t < CHUNK / 4; ++t) {
        int k = t * 4 + sub;
        uint4 bx = boxes_s[k];
        unsigned long long A = (unsigned long long)bx.x | ((unsigned long long)bx.y << 32);
        unsigned long long B = (unsigned long long)bx.z | ((unsigned long long)bx.w << 32);
        unsigned long long t1 = PVG - A;
        unsigned long long t2 = B - PV;
        if (((t1 & t2) & GUARD64) == GUARD64) {
            int gidx = c * CHUNK + k;
            float4 a0 = gd[gidx * 4 + 0];
            float4 a1 = gd[gidx * 4 + 1];
            float4 a2 = gd[gidx * 4 + 2];
            float4 a3 = gd[gidx * 4 + 3];
            float s1 = pp0 * a0.x;
            s1 = fmaf(pp1, a0.y, s1);
            s1 = fmaf(pp2, a0.z, s1);
            s1 = fmaf(pp1, a0.w, s1);
            s1 = fmaf(pp4, a1.x, s1);
            s1 = fmaf(pp5, a1.y, s1);
            s1 = fmaf(pp2, a1.z, s1);
            s1 = fmaf(pp5, a1.w, s1);
            s1 = fmaf(pp8, a2.x, s1);
            float d = px * a2.y;
            d = fmaf(py, a2.z, d);
            d = fmaf(pz, a2.w, d);
            float quad = fmaf(-2.0f, d, s1) + a3.x;
            float sc = fmaf(-0.5f, quad, a3.y);
            if (sc > tv[K_TOP - 1]) {
                tv[K_TOP - 1] = sc;
                ti[K_TOP - 1] = gidx;
#pragma unroll
                for (int j = K_TOP - 1; j > 0; --j) {
                    if (tv[j] > tv[j - 1]) {
                        float fv = tv[j]; tv[j] = tv[j - 1]; tv[j - 1] = fv;
                        int iv = ti[j]; ti[j] = ti[j - 1]; ti[j - 1] = iv;
                    }
                }
            }
        }
    }

    // fold the 4 sub-lane lists: xor-1 merge, then xor-2 merge
    float ov[K_TOP];
    int oi[K_TOP];
#pragma unroll
    for (int j = 0; j < K_TOP; ++j) { ov[j] = __shfl_xor(tv[j], 1); oi[j] = __shfl_xor(ti[j], 1); }
    merge8(tv, ti, ov, oi);
#pragma unroll
    for (int j = 0; j < K_TOP; ++j) { ov[j] = __shfl_xor(tv[j], 2); oi[j] = __shfl_xor(ti[j], 2); }
    merge8(tv, ti, ov, oi);

    if (sub == 0) {
        float2* cand = (float2*)(ws + CANDOFF);
#pragma unroll
        for (int j = 0; j < K_TOP; ++j)
            cand[(size_t)(c * K_TOP + j) * P_N + p] = make_float2(tv[j], __int_as_float(ti[j]));
    }
}

// Merge: fold NCHUNK sorted lists per point; ids (as float values) then probs.
__global__ __launch_bounds__(64) void k_merge(const float* __restrict__ ws, float* __restrict__ out) {
    int p = blockIdx.x * 64 + threadIdx.x;
    const float2* cand = (const float2*)(ws + CANDOFF);
    float tv[K_TOP];
    int ti[K_TOP];
#pragma unroll
    for (int j = 0; j < K_TOP; ++j) { tv[j] = -INFINITY; ti[j] = 0x7fffffff; }
    for (int c = 0; c < NCHUNK; ++c) {
#pragma unroll
        for (int j = 0; j < K_TOP; ++j) {
            float2 r = cand[(size_t)(c * K_TOP + j) * P_N + p];
            float v = r.x;
            int idx = __float_as_int(r.y);
            bool better = (v > tv[K_TOP - 1]) || (v == tv[K_TOP - 1] && idx < ti[K_TOP - 1]);
            if (better) {
                tv[K_TOP - 1] = v;
                ti[K_TOP - 1] = idx;
#pragma unroll
                for (int t = K_TOP - 1; t > 0; --t) {
                    bool sw = (tv[t] > tv[t - 1]) || (tv[t] == tv[t - 1] && ti[t] < ti[t - 1]);
                    if (sw) {
                        float fv = tv[t]; tv[t] = tv[t - 1]; tv[t - 1] = fv;
                        int iv = ti[t]; ti[t] = ti[t - 1]; ti[t - 1] = iv;
                    }
                }
            }
        }
    }
#pragma unroll
    for (int j = 0; j < K_TOP; ++j) {
        bool fin = tv[j] > -INFINITY;
        out[p * K_TOP + j] = fin ? (float)ti[j] : -1.0f;
        out[P_N * K_TOP + p * K_TOP + j] = fin ? expf(tv[j]) : 0.0f;
    }
}

extern "C" void kernel_launch(void* const* d_in, const int* in_sizes, int n_in,
                              void* d_out, int out_size, void* d_ws, size_t ws_size,
                              hipStream_t stream) {
    const float* pos = (const float*)d_in[0];
    const float* scl = (const float*)d_in[1];
    const float* quat = (const float*)d_in[2];
    const float* pts = (const float*)d_in[3];
    float* ws = (float*)d_ws;
    float* out = (float*)d_out;

    k_stats<<<dim3(7), dim3(1024), 0, stream>>>(pos, scl, quat, ws);
    k_prep<<<dim3(G_N / 256), dim3(256), 0, stream>>>(pos, scl, quat, ws);
    k_score<<<dim3(P_N / 64, NCHUNK), dim3(256), 0, stream>>>(pts, ws);
    k_merge<<<dim3(P_N / 64), dim3(64), 0, stream>>>(ws, out);
}

// Round 4
// 124.832 us; speedup vs baseline: 1.3598x; 1.1162x over previous
//
#include <hip/hip_runtime.h>
#include <math.h>

// Keep mul/add rounding deterministic in the discrete-sensitive chains
// (radius -> quantile -> grid). Score math uses explicit fmaf.
#pragma clang fp contract(off)

#define G_N 2048
#define P_N 16384
#define K_TOP 8
#define NSUB 8               // sub-lanes per point
#define PPB 32               // points per block (256 threads / 8 sub-lanes)

// SWAR guard bits: fields at bits 0/21/42, guard = bit 20 of each field.
#define GUARD64 ((1ull << 20) | (1ull << 41) | (1ull << 62))

__device__ __forceinline__ void quat_R(const float* quat, int g, float R[3][3]) {
    float q0 = quat[g * 4 + 0], q1 = quat[g * 4 + 1], q2 = quat[g * 4 + 2], q3 = quat[g * 4 + 3];
    float nrm = sqrtf(q0 * q0 + q1 * q1 + q2 * q2 + q3 * q3);
    float w = q0 / nrm, x = q1 / nrm, y = q2 / nrm, z = q3 / nrm;
    R[0][0] = 1.0f - 2.0f * (y * y + z * z);
    R[0][1] = 2.0f * (x * y - w * z);
    R[0][2] = 2.0f * (x * z + w * y);
    R[1][0] = 2.0f * (x * y + w * z);
    R[1][1] = 1.0f - 2.0f * (x * x + z * z);
    R[1][2] = 2.0f * (y * z - w * x);
    R[2][0] = 2.0f * (x * z - w * y);
    R[2][1] = 2.0f * (y * z + w * x);
    R[2][2] = 1.0f - 2.0f * (x * x + y * y);
}

__device__ __forceinline__ float radius_axis(const float R[3][3], float s2x, float s2y, float s2z, int a) {
    float dc = (R[a][0] * R[a][0]) * s2x + (R[a][1] * R[a][1]) * s2y + (R[a][2] * R[a][2]) * s2z;
    return sqrtf(7.8147279f) * sqrtf(dc);
}

// Stats: 7 blocks; recompute stat array inline, bitonic sort in LDS, emit quantile.
// 0-2: quantile(min_c[:,a],0.01); 3-5: quantile(max_c[:,a],0.99); 6: median(radius_x)
__global__ __launch_bounds__(1024) void k_stats(const float* __restrict__ pos,
                                                const float* __restrict__ scl,
                                                const float* __restrict__ quat,
                                                float* __restrict__ ws) {
    __shared__ float buf[G_N];
    int which = blockIdx.x;
    int tid = threadIdx.x;
    int a = (which < 3) ? which : (which < 6 ? which - 3 : 0);
    for (int g = tid; g < G_N; g += 1024) {
        float R[3][3];
        quat_R(quat, g, R);
        float sx = scl[g * 3 + 0], sy = scl[g * 3 + 1], sz = scl[g * 3 + 2];
        float rad = radius_axis(R, sx * sx, sy * sy, sz * sz, a);
        float v;
        if (which < 3)      v = pos[g * 3 + a] - rad;
        else if (which < 6) v = pos[g * 3 + a] + rad;
        else                v = rad;
        buf[g] = v;
    }
    __syncthreads();
    for (int k = 2; k <= G_N; k <<= 1) {
        for (int j = k >> 1; j > 0; j >>= 1) {
            for (int i = tid; i < G_N; i += 1024) {
                int partner = i ^ j;
                if (partner > i) {
                    bool up = ((i & k) == 0);
                    float va = buf[i], vb = buf[partner];
                    if ((va > vb) == up) { buf[i] = vb; buf[partner] = va; }
                }
            }
            __syncthreads();
        }
    }
    if (tid == 0) {
        float qq;
        if (which < 3) qq = 0.01f * 2047.0f;
        else if (which < 6) qq = 0.99f * 2047.0f;
        else qq = 0.5f * 2047.0f;
        int lo = (int)floorf(qq);
        float fr = qq - (float)lo;
        ws[which] = buf[lo] * (1.0f - fr) + buf[lo + 1] * fr;
    }
}

// compare-exchange on (value desc, idx asc): better stays in (va,ia)
__device__ __forceinline__ void ce(float& va, int& ia, float& vb, int& ib) {
    bool keep = (va > vb) || (va == vb && ia < ib);
    float v0 = keep ? va : vb, v1 = keep ? vb : va;
    int i0 = keep ? ia : ib, i1 = keep ? ib : ia;
    va = v0; vb = v1; ia = i0; ib = i1;
}

// merge two sorted-desc top-8 lists (strict total order: idx unique) -> sorted-desc top-8
__device__ __forceinline__ void merge_sorted8(float tv[K_TOP], int ti[K_TOP],
                                              float ov[K_TOP], int oi[K_TOP]) {
    // half-cleaner vs reversed partner: keep the 8 winners (bitonic)
#pragma unroll
    for (int j = 0; j < K_TOP; ++j) ce(tv[j], ti[j], ov[K_TOP - 1 - j], oi[K_TOP - 1 - j]);
    // clean bitonic 8 -> sorted desc
    ce(tv[0], ti[0], tv[4], ti[4]); ce(tv[1], ti[1], tv[5], ti[5]);
    ce(tv[2], ti[2], tv[6], ti[6]); ce(tv[3], ti[3], tv[7], ti[7]);
    ce(tv[0], ti[0], tv[2], ti[2]); ce(tv[1], ti[1], tv[3], ti[3]);
    ce(tv[4], ti[4], tv[6], ti[6]); ce(tv[5], ti[5], tv[7], ti[7]);
    ce(tv[0], ti[0], tv[1], ti[1]); ce(tv[2], ti[2], tv[3], ti[3]);
    ce(tv[4], ti[4], tv[5], ti[5]); ce(tv[6], ti[6], tv[7], ti[7]);
}

// Fused kernel: build all 2048 SWAR boxes in LDS, scan (8 sub-lanes/point),
// score on-the-fly on rare mask hits, shfl-merge, write output directly.
__global__ __launch_bounds__(256) void k_score(const float* __restrict__ pos,
                                               const float* __restrict__ scl,
                                               const float* __restrict__ quat,
                                               const float* __restrict__ pts,
                                               const float* __restrict__ ws,
                                               float* __restrict__ out) {
    __shared__ uint4 boxes_s[G_N];

    // grid params from stats header (same f32 chain everywhere => same bits)
    float gmn[3], vox;
#pragma unroll
    for (int t = 0; t < 3; ++t) {
        float lo = ws[t], hi = ws[3 + t];
        float size = hi - lo;
        gmn[t] = lo - 0.1f * size;
    }
    vox = ws[6] * 3.0f;

    // build boxes: each thread packs 8 gaussians
#pragma unroll
    for (int i = 0; i < 8; ++i) {
        int g = threadIdx.x + i * 256;
        float R[3][3];
        quat_R(quat, g, R);
        float sx = scl[g * 3 + 0], sy = scl[g * 3 + 1], sz = scl[g * 3 + 2];
        float s2x = sx * sx, s2y = sy * sy, s2z = sz * sz;
        int gmini[3], gmaxi[3];
        long long nv = 1;
#pragma unroll
        for (int t = 0; t < 3; ++t) {
            float rad = radius_axis(R, s2x, s2y, s2z, t);
            float p = pos[g * 3 + t];
            int lo = (int)floorf(((p - rad) - gmn[t]) / vox);
            int hi = (int)floorf(((p + rad) - gmn[t]) / vox);
            lo = lo < 0 ? 0 : (lo > 1023 ? 1023 : lo);
            hi = hi < 0 ? 0 : (hi > 1023 ? 1023 : hi);
            gmini[t] = lo; gmaxi[t] = hi;
            nv *= (long long)(hi - lo + 1);
        }
        if (nv > 64) {           // oversized: passes everything incl. the 1024 sentinel
            gmini[0] = gmini[1] = gmini[2] = 0;
            gmaxi[0] = gmaxi[1] = gmaxi[2] = 2047;
        }
        unsigned long long A = (unsigned long long)gmini[0]
                             | ((unsigned long long)gmini[1] << 21)
                             | ((unsigned long long)gmini[2] << 42);
        unsigned long long B = ((unsigned long long)gmaxi[0]
                             | ((unsigned long long)gmaxi[1] << 21)
                             | ((unsigned long long)gmaxi[2] << 42)) | GUARD64;
        boxes_s[g] = make_uint4((unsigned)(A & 0xffffffffu), (unsigned)(A >> 32),
                                (unsigned)(B & 0xffffffffu), (unsigned)(B >> 32));
    }
    __syncthreads();

    int sub = threadIdx.x & (NSUB - 1);
    int p = blockIdx.x * PPB + (threadIdx.x >> 3);
    float px = pts[p * 3 + 0], py = pts[p * 3 + 1], pz = pts[p * 3 + 2];
    float fpx = floorf((px - gmn[0]) / vox);
    float fpy = floorf((py - gmn[1]) / vox);
    float fpz = floorf((pz - gmn[2]) / vox);
    // out-of-range sentinel 1024: fails every real box (max<=1023), passes oversized (2047)
    unsigned fx = (fpx < 0.0f || fpx > 1023.0f) ? 1024u : (unsigned)fpx;
    unsigned fy = (fpy < 0.0f || fpy > 1023.0f) ? 1024u : (unsigned)fpy;
    unsigned fz = (fpz < 0.0f || fpz > 1023.0f) ? 1024u : (unsigned)fpz;
    unsigned long long PV = (unsigned long long)fx
                          | ((unsigned long long)fy << 21)
                          | ((unsigned long long)fz << 42);
    unsigned long long PVG = PV | GUARD64;

    float pp0 = px * px, pp1 = px * py, pp2 = px * pz;
    float pp4 = py * py, pp5 = py * pz, pp8 = pz * pz;

    float tv[K_TOP];
    int ti[K_TOP];
#pragma unroll
    for (int j = 0; j < K_TOP; ++j) { tv[j] = -INFINITY; ti[j] = 0x7fffffff; }

#pragma unroll 8
    for (int t = 0; t < G_N / NSUB; ++t) {
        int k = t * NSUB + sub;
        uint4 bx = boxes_s[k];
        unsigned long long A = (unsigned long long)bx.x | ((unsigned long long)bx.y << 32);
        unsigned long long B = (unsigned long long)bx.z | ((unsigned long long)bx.w << 32);
        unsigned long long d1 = PVG - A;
        unsigned long long d2 = B - PV;
        if (((d1 & d2) & GUARD64) == GUARD64) {
            // rare: compute score on the fly (same expressions as the old k_prep)
            float R[3][3];
            quat_R(quat, k, R);
            float sx = scl[k * 3 + 0], sy = scl[k * 3 + 1], sz = scl[k * 3 + 2];
            float inv2x = 1.0f / (sx * sx), inv2y = 1.0f / (sy * sy), inv2z = 1.0f / (sz * sz);
            float C[3][3];
#pragma unroll
            for (int i = 0; i < 3; ++i) {
                float t0 = R[i][0] * inv2x, t1 = R[i][1] * inv2y, t2 = R[i][2] * inv2z;
#pragma unroll
                for (int kk = 0; kk < 3; ++kk)
                    C[i][kk] = t0 * R[kk][0] + t1 * R[kk][1] + t2 * R[kk][2];
            }
            float gx = pos[k * 3 + 0], gy = pos[k * 3 + 1], gz = pos[k * 3 + 2];
            float b0 = C[0][0] * gx + C[0][1] * gy + C[0][2] * gz;
            float b1 = C[1][0] * gx + C[1][1] * gy + C[1][2] * gz;
            float b2 = C[2][0] * gx + C[2][1] * gy + C[2][2] * gz;
            float c0 = b0 * gx + b1 * gy + b2 * gz;
            float log_norm = -2.7568155996140179f - (logf(sx) + logf(sy) + logf(sz));
            float s1 = pp0 * C[0][0];
            s1 = fmaf(pp1, C[0][1], s1);
            s1 = fmaf(pp2, C[0][2], s1);
            s1 = fmaf(pp1, C[1][0], s1);
            s1 = fmaf(pp4, C[1][1], s1);
            s1 = fmaf(pp5, C[1][2], s1);
            s1 = fmaf(pp2, C[2][0], s1);
            s1 = fmaf(pp5, C[2][1], s1);
            s1 = fmaf(pp8, C[2][2], s1);
            float d = px * b0;
            d = fmaf(py, b1, d);
            d = fmaf(pz, b2, d);
            float quad = fmaf(-2.0f, d, s1) + c0;
            float sc = fmaf(-0.5f, quad, log_norm);
            if (sc > tv[K_TOP - 1]) {
                tv[K_TOP - 1] = sc;
                ti[K_TOP - 1] = k;
#pragma unroll
                for (int j = K_TOP - 1; j > 0; --j) {
                    if (tv[j] > tv[j - 1]) {
                        float fv = tv[j]; tv[j] = tv[j - 1]; tv[j - 1] = fv;
                        int iv = ti[j]; ti[j] = ti[j - 1]; ti[j - 1] = iv;
                    }
                }
            }
        }
    }

    // fold 8 sub-lane lists: xor 1, 2, 4
    float ov[K_TOP];
    int oi[K_TOP];
#pragma unroll
    for (int j = 0; j < K_TOP; ++j) { ov[j] = __shfl_xor(tv[j], 1); oi[j] = __shfl_xor(ti[j], 1); }
    merge_sorted8(tv, ti, ov, oi);
#pragma unroll
    for (int j = 0; j < K_TOP; ++j) { ov[j] = __shfl_xor(tv[j], 2); oi[j] = __shfl_xor(ti[j], 2); }
    merge_sorted8(tv, ti, ov, oi);
#pragma unroll
    for (int j = 0; j < K_TOP; ++j) { ov[j] = __shfl_xor(tv[j], 4); oi[j] = __shfl_xor(ti[j], 4); }
    merge_sorted8(tv, ti, ov, oi);

    if (sub == 0) {
#pragma unroll
        for (int j = 0; j < K_TOP; ++j) {
            bool fin = tv[j] > -INFINITY;
            out[p * K_TOP + j] = fin ? (float)ti[j] : -1.0f;
            out[P_N * K_TOP + p * K_TOP + j] = fin ? expf(tv[j]) : 0.0f;
        }
    }
}

extern "C" void kernel_launch(void* const* d_in, const int* in_sizes, int n_in,
                              void* d_out, int out_size, void* d_ws, size_t ws_size,
                              hipStream_t stream) {
    const float* pos = (const float*)d_in[0];
    const float* scl = (const float*)d_in[1];
    const float* quat = (const float*)d_in[2];
    const float* pts = (const float*)d_in[3];
    float* ws = (float*)d_ws;
    float* out = (float*)d_out;

    k_stats<<<dim3(7), dim3(1024), 0, stream>>>(pos, scl, quat, ws);
    k_score<<<dim3(P_N / PPB), dim3(256), 0, stream>>>(pos, scl, quat, pts, ws, out);
}

// Round 5
// 104.957 us; speedup vs baseline: 1.6173x; 1.1894x over previous
//
#include <hip/hip_runtime.h>
#include <math.h>

// Keep mul/add rounding deterministic in the discrete-sensitive chains
// (radius -> quantile -> grid). Score math uses explicit fmaf.
#pragma clang fp contract(off)

#define G_N 2048
#define P_N 16384
#define K_TOP 8
#define NBUCK 32768          // spatial-hash buckets (power of 2)
#define BCAP 128             // ids per bucket; overflow -> exact full scan

// SWAR guard bits: fields at bits 0/21/42, guard = bit 20 of each field.
#define GUARD64 ((1ull << 20) | (1ull << 41) | (1ull << 62))

// u32-offset layout in ws:
#define OFF_CNT 16                       // bucket counts [NBUCK]
#define OFF_OVC (OFF_CNT + NBUCK)        // oversized count [1]
#define OFF_OVL (OFF_OVC + 1)            // oversized ids [G_N]
#define OFF_ENT (OFF_OVL + G_N)          // bucket entries [NBUCK*BCAP]
#define OFF_BOX (OFF_ENT + NBUCK * BCAP) // SWAR boxes uint4 [G_N]

__device__ __forceinline__ void quat_R(const float* quat, int g, float R[3][3]) {
    float q0 = quat[g * 4 + 0], q1 = quat[g * 4 + 1], q2 = quat[g * 4 + 2], q3 = quat[g * 4 + 3];
    float nrm = sqrtf(q0 * q0 + q1 * q1 + q2 * q2 + q3 * q3);
    float w = q0 / nrm, x = q1 / nrm, y = q2 / nrm, z = q3 / nrm;
    R[0][0] = 1.0f - 2.0f * (y * y + z * z);
    R[0][1] = 2.0f * (x * y - w * z);
    R[0][2] = 2.0f * (x * z + w * y);
    R[1][0] = 2.0f * (x * y + w * z);
    R[1][1] = 1.0f - 2.0f * (x * x + z * z);
    R[1][2] = 2.0f * (y * z - w * x);
    R[2][0] = 2.0f * (x * z - w * y);
    R[2][1] = 2.0f * (y * z + w * x);
    R[2][2] = 1.0f - 2.0f * (x * x + y * y);
}

__device__ __forceinline__ float radius_axis(const float R[3][3], float s2x, float s2y, float s2z, int a) {
    float dc = (R[a][0] * R[a][0]) * s2x + (R[a][1] * R[a][1]) * s2y + (R[a][2] * R[a][2]) * s2z;
    return sqrtf(7.8147279f) * sqrtf(dc);
}

__device__ __forceinline__ void grid_params(const float* ws, float gmn[3], float& vox) {
#pragma unroll
    for (int t = 0; t < 3; ++t) {
        float lo = ws[t], hi = ws[3 + t];
        float size = hi - lo;
        gmn[t] = lo - 0.1f * size;
    }
    vox = ws[6] * 3.0f;
}

// full score for gaussian g at point (px,py,pz) — exact R4 expression chain
__device__ __forceinline__ float score_g(const float* __restrict__ pos, const float* __restrict__ scl,
                                         const float* __restrict__ quat, int g,
                                         float px, float py, float pz,
                                         float pp0, float pp1, float pp2,
                                         float pp4, float pp5, float pp8) {
    float R[3][3];
    quat_R(quat, g, R);
    float sx = scl[g * 3 + 0], sy = scl[g * 3 + 1], sz = scl[g * 3 + 2];
    float inv2x = 1.0f / (sx * sx), inv2y = 1.0f / (sy * sy), inv2z = 1.0f / (sz * sz);
    float C[3][3];
#pragma unroll
    for (int i = 0; i < 3; ++i) {
        float t0 = R[i][0] * inv2x, t1 = R[i][1] * inv2y, t2 = R[i][2] * inv2z;
#pragma unroll
        for (int k = 0; k < 3; ++k)
            C[i][k] = t0 * R[k][0] + t1 * R[k][1] + t2 * R[k][2];
    }
    float gx = pos[g * 3 + 0], gy = pos[g * 3 + 1], gz = pos[g * 3 + 2];
    float b0 = C[0][0] * gx + C[0][1] * gy + C[0][2] * gz;
    float b1 = C[1][0] * gx + C[1][1] * gy + C[1][2] * gz;
    float b2 = C[2][0] * gx + C[2][1] * gy + C[2][2] * gz;
    float c0 = b0 * gx + b1 * gy + b2 * gz;
    float log_norm = -2.7568155996140179f - (logf(sx) + logf(sy) + logf(sz));
    float s1 = pp0 * C[0][0];
    s1 = fmaf(pp1, C[0][1], s1);
    s1 = fmaf(pp2, C[0][2], s1);
    s1 = fmaf(pp1, C[1][0], s1);
    s1 = fmaf(pp4, C[1][1], s1);
    s1 = fmaf(pp5, C[1][2], s1);
    s1 = fmaf(pp2, C[2][0], s1);
    s1 = fmaf(pp5, C[2][1], s1);
    s1 = fmaf(pp8, C[2][2], s1);
    float d = px * b0;
    d = fmaf(py, b1, d);
    d = fmaf(pz, b2, d);
    float quad = fmaf(-2.0f, d, s1) + c0;
    return fmaf(-0.5f, quad, log_norm);
}

// Stats: blocks 0-6 bitonic-sort one stat array and emit the quantile; block 7
// zeros the hash-table counters (ws is re-poisoned before every launch).
__global__ __launch_bounds__(1024) void k_stats(const float* __restrict__ pos,
                                                const float* __restrict__ scl,
                                                const float* __restrict__ quat,
                                                float* __restrict__ ws) {
    int which = blockIdx.x;
    int tid = threadIdx.x;
    if (which == 7) {
        unsigned* u = (unsigned*)ws;
        for (int i = tid; i < NBUCK; i += 1024) u[OFF_CNT + i] = 0u;
        if (tid == 0) u[OFF_OVC] = 0u;
        return;
    }
    __shared__ float buf[G_N];
    int a = (which < 3) ? which : (which < 6 ? which - 3 : 0);
    for (int g = tid; g < G_N; g += 1024) {
        float R[3][3];
        quat_R(quat, g, R);
        float sx = scl[g * 3 + 0], sy = scl[g * 3 + 1], sz = scl[g * 3 + 2];
        float rad = radius_axis(R, sx * sx, sy * sy, sz * sz, a);
        float v;
        if (which < 3)      v = pos[g * 3 + a] - rad;
        else if (which < 6) v = pos[g * 3 + a] + rad;
        else                v = rad;
        buf[g] = v;
    }
    __syncthreads();
    for (int k = 2; k <= G_N; k <<= 1) {
        for (int j = k >> 1; j > 0; j >>= 1) {
            for (int i = tid; i < G_N; i += 1024) {
                int partner = i ^ j;
                if (partner > i) {
                    bool up = ((i & k) == 0);
                    float va = buf[i], vb = buf[partner];
                    if ((va > vb) == up) { buf[i] = vb; buf[partner] = va; }
                }
            }
            __syncthreads();
        }
    }
    if (tid == 0) {
        float qq;
        if (which < 3) qq = 0.01f * 2047.0f;
        else if (which < 6) qq = 0.99f * 2047.0f;
        else qq = 0.5f * 2047.0f;
        int lo = (int)floorf(qq);
        float fr = qq - (float)lo;
        ws[which] = buf[lo] * (1.0f - fr) + buf[lo + 1] * fr;
    }
}

// Build: per-gaussian SWAR box + spatial-hash rasterization.
__global__ __launch_bounds__(256) void k_build(const float* __restrict__ pos,
                                               const float* __restrict__ scl,
                                               const float* __restrict__ quat,
                                               float* __restrict__ ws) {
    int g = blockIdx.x * blockDim.x + threadIdx.x;
    if (g >= G_N) return;
    float gmn[3], vox;
    grid_params(ws, gmn, vox);

    float R[3][3];
    quat_R(quat, g, R);
    float sx = scl[g * 3 + 0], sy = scl[g * 3 + 1], sz = scl[g * 3 + 2];
    float s2x = sx * sx, s2y = sy * sy, s2z = sz * sz;
    int gmini[3], gmaxi[3];
    long long nv = 1;
#pragma unroll
    for (int t = 0; t < 3; ++t) {
        float rad = radius_axis(R, s2x, s2y, s2z, t);
        float p = pos[g * 3 + t];
        int lo = (int)floorf(((p - rad) - gmn[t]) / vox);
        int hi = (int)floorf(((p + rad) - gmn[t]) / vox);
        lo = lo < 0 ? 0 : (lo > 1023 ? 1023 : lo);
        hi = hi < 0 ? 0 : (hi > 1023 ? 1023 : hi);
        gmini[t] = lo; gmaxi[t] = hi;
        nv *= (long long)(hi - lo + 1);
    }
    unsigned* u = (unsigned*)ws;
    bool oversized = nv > 64;
    if (oversized) {
        unsigned slot = atomicAdd(&u[OFF_OVC], 1u);
        u[OFF_OVL + slot] = (unsigned)g;
        gmini[0] = gmini[1] = gmini[2] = 0;
        gmaxi[0] = gmaxi[1] = gmaxi[2] = 2047;
    } else {
        for (int z = gmini[2]; z <= gmaxi[2]; ++z)
            for (int y = gmini[1]; y <= gmaxi[1]; ++y)
                for (int x = gmini[0]; x <= gmaxi[0]; ++x) {
                    unsigned h = ((unsigned)x * 73856093u ^ (unsigned)y * 19349663u
                                ^ (unsigned)z * 83492791u) & (NBUCK - 1);
                    unsigned old = atomicAdd(&u[OFF_CNT + h], 1u);
                    if (old < BCAP) u[OFF_ENT + h * BCAP + old] = (unsigned)g;
                }
    }
    unsigned long long A = (unsigned long long)gmini[0]
                         | ((unsigned long long)gmini[1] << 21)
                         | ((unsigned long long)gmini[2] << 42);
    unsigned long long B = ((unsigned long long)gmaxi[0]
                         | ((unsigned long long)gmaxi[1] << 21)
                         | ((unsigned long long)gmaxi[2] << 42)) | GUARD64;
    uint4* bx = (uint4*)(u + OFF_BOX);
    bx[g] = make_uint4((unsigned)(A & 0xffffffffu), (unsigned)(A >> 32),
                       (unsigned)(B & 0xffffffffu), (unsigned)(B >> 32));
}

// dedupe + strict-total-order (score desc, id asc) top-8 insert
__device__ __forceinline__ void ins8(float tv[K_TOP], int ti[K_TOP], float sc, int id) {
    bool dup = false;
#pragma unroll
    for (int j = 0; j < K_TOP; ++j) dup |= (ti[j] == id);
    if (dup) return;
    bool better = (sc > tv[K_TOP - 1]) || (sc == tv[K_TOP - 1] && id < ti[K_TOP - 1]);
    if (!better) return;
    tv[K_TOP - 1] = sc;
    ti[K_TOP - 1] = id;
#pragma unroll
    for (int j = K_TOP - 1; j > 0; --j) {
        bool sw = (tv[j] > tv[j - 1]) || (tv[j] == tv[j - 1] && ti[j] < ti[j - 1]);
        if (sw) {
            float fv = tv[j]; tv[j] = tv[j - 1]; tv[j - 1] = fv;
            int iv = ti[j]; ti[j] = ti[j - 1]; ti[j - 1] = iv;
        }
    }
}

// Match: one thread per point — bucket lookup + exact box verify + rare score.
__global__ __launch_bounds__(64) void k_match(const float* __restrict__ pos,
                                              const float* __restrict__ scl,
                                              const float* __restrict__ quat,
                                              const float* __restrict__ pts,
                                              const float* __restrict__ ws,
                                              float* __restrict__ out) {
    int p = blockIdx.x * 64 + threadIdx.x;
    float gmn[3], vox;
    grid_params(ws, gmn, vox);
    float px = pts[p * 3 + 0], py = pts[p * 3 + 1], pz = pts[p * 3 + 2];
    float fpx = floorf((px - gmn[0]) / vox);
    float fpy = floorf((py - gmn[1]) / vox);
    float fpz = floorf((pz - gmn[2]) / vox);
    bool valid = (fpx >= 0.0f) & (fpx <= 1023.0f) & (fpy >= 0.0f) & (fpy <= 1023.0f)
               & (fpz >= 0.0f) & (fpz <= 1023.0f);

    float pp0 = px * px, pp1 = px * py, pp2 = px * pz;
    float pp4 = py * py, pp5 = py * pz, pp8 = pz * pz;

    float tv[K_TOP];
    int ti[K_TOP];
#pragma unroll
    for (int j = 0; j < K_TOP; ++j) { tv[j] = -INFINITY; ti[j] = 0x7fffffff; }

    const unsigned* u = (const unsigned*)ws;
    const uint4* bx = (const uint4*)(u + OFF_BOX);

    if (valid) {
        int vx = (int)fpx, vy = (int)fpy, vz = (int)fpz;
        unsigned long long PV = (unsigned long long)(unsigned)vx
                              | ((unsigned long long)(unsigned)vy << 21)
                              | ((unsigned long long)(unsigned)vz << 42);
        unsigned long long PVG = PV | GUARD64;
        unsigned h = ((unsigned)vx * 73856093u ^ (unsigned)vy * 19349663u
                    ^ (unsigned)vz * 83492791u) & (NBUCK - 1);
        unsigned cnt = u[OFF_CNT + h];
        if (cnt <= BCAP) {
            for (unsigned i = 0; i < cnt; ++i) {
                int g = (int)u[OFF_ENT + h * BCAP + i];
                uint4 b4 = bx[g];
                unsigned long long A = (unsigned long long)b4.x | ((unsigned long long)b4.y << 32);
                unsigned long long B = (unsigned long long)b4.z | ((unsigned long long)b4.w << 32);
                if ((((PVG - A) & (B - PV)) & GUARD64) == GUARD64) {
                    float sc = score_g(pos, scl, quat, g, px, py, pz, pp0, pp1, pp2, pp4, pp5, pp8);
                    ins8(tv, ti, sc, g);
                }
            }
        } else {
            // bucket overflow: exact full scan (covers every gaussian incl. oversized)
            for (int g = 0; g < G_N; ++g) {
                uint4 b4 = bx[g];
                unsigned long long A = (unsigned long long)b4.x | ((unsigned long long)b4.y << 32);
                unsigned long long B = (unsigned long long)b4.z | ((unsigned long long)b4.w << 32);
                if ((((PVG - A) & (B - PV)) & GUARD64) == GUARD64) {
                    float sc = score_g(pos, scl, quat, g, px, py, pz, pp0, pp1, pp2, pp4, pp5, pp8);
                    ins8(tv, ti, sc, g);
                }
            }
        }
    }
    // oversized gaussians pass for every point (dedupe handles overlap with full scan)
    unsigned ovc = u[OFF_OVC];
    for (unsigned i = 0; i < ovc; ++i) {
        int g = (int)u[OFF_OVL + i];
        float sc = score_g(pos, scl, quat, g, px, py, pz, pp0, pp1, pp2, pp4, pp5, pp8);
        ins8(tv, ti, sc, g);
    }

#pragma unroll
    for (int j = 0; j < K_TOP; ++j) {
        bool fin = tv[j] > -INFINITY;
        out[p * K_TOP + j] = fin ? (float)ti[j] : -1.0f;
        out[P_N * K_TOP + p * K_TOP + j] = fin ? expf(tv[j]) : 0.0f;
    }
}

extern "C" void kernel_launch(void* const* d_in, const int* in_sizes, int n_in,
                              void* d_out, int out_size, void* d_ws, size_t ws_size,
                              hipStream_t stream) {
    const float* pos = (const float*)d_in[0];
    const float* scl = (const float*)d_in[1];
    const float* quat = (const float*)d_in[2];
    const float* pts = (const float*)d_in[3];
    float* ws = (float*)d_ws;
    float* out = (float*)d_out;

    k_stats<<<dim3(8), dim3(1024), 0, stream>>>(pos, scl, quat, ws);
    k_build<<<dim3(G_N / 256), dim3(256), 0, stream>>>(pos, scl, quat, ws);
    k_match<<<dim3(P_N / 64), dim3(64), 0, stream>>>(pos, scl, quat, pts, ws, out);
}